// Round 4
// baseline (182.372 us; speedup 1.0000x reference)
//
#include <hip/hip_runtime.h>

#define N_GAUSS 1024
#define H_DIM 768
#define W_DIM 768

typedef float v2f __attribute__((ext_vector_type(2)));

// gpa[n] = {mx, my, A, Bc}; gpb[n] = {D, wr, wg, wb}
// A, Bc, D carry the -0.5*log2(e) factor so the hot loop uses raw exp2.
__global__ __launch_bounds__(256) void prep_kernel(
    const float* __restrict__ means, const float* __restrict__ covs,
    const float* __restrict__ colors, float4* __restrict__ gpa,
    float4* __restrict__ gpb) {
  int n = blockIdx.x * 256 + threadIdx.x;
  if (n >= N_GAUSS) return;
  float mx = means[n * 2 + 0];
  float my = means[n * 2 + 1];
  float a = covs[n * 4 + 0];
  float b = covs[n * 4 + 1];
  float c = covs[n * 4 + 2];
  float d = covs[n * 4 + 3];
  float inv = 1.0f / (a * d - b * c);
  const float L = -0.72134752044448170368f;  // -0.5 * log2(e)
  float A  = L * d * inv;
  float Bc = -L * (b + c) * inv;
  float D  = L * a * inv;
  float cr = colors[n * 4 + 0];
  float cg = colors[n * 4 + 1];
  float cb = colors[n * 4 + 2];
  float al = colors[n * 4 + 3];
  float wr = al / (1.0f + expf(-cr));
  float wg = al / (1.0f + expf(-cg));
  float wb = al / (1.0f + expf(-cb));
  gpa[n] = make_float4(mx, my, A, Bc);
  gpb[n] = make_float4(D, wr, wg, wb);
}

// 4 px/thread, 64-thread (1-wave) blocks, 2304 blocks = exactly 9 resident
// waves/CU, no dispatch tail. Per-row quadratic coeffs {c1,c0} in LDS
// (1 broadcast ds_read_b64/gaussian); {D,wr,wg,wb} via uniform s_load.
// Hot loop per gaussian (4 px): 4 pk_fma (q) + 4 exp + 6 pk_fma (acc).
__global__ __launch_bounds__(64) void render_kernel(
    const float4* __restrict__ gpa, const float4* __restrict__ gpb,
    float* __restrict__ out) {
  __shared__ v2f cc[N_GAUSS];  // {c1, c0} per gaussian for this row

  const int h   = blockIdx.x / 3;
  const int seg = blockIdx.x % 3;
  const int t   = threadIdx.x;  // 0..63
  const float scale = 1.0f / 767.0f;
  const float x = (float)h * scale;

  // Row-coefficient prep: 16 gaussians per thread.
#pragma unroll
  for (int i = 0; i < N_GAUSS / 64; ++i) {
    int n = i * 64 + t;
    float4 p = gpa[n];                 // mx, my, A, Bc
    float D = gpb[n].x;
    float dx = x - p.x;
    float qa = p.z * dx * dx;          // A*dx^2
    float qb = p.w * dx;               // Bc*dx
    float c1 = fmaf(-2.0f * D, p.y, qb);
    float c0 = fmaf(fmaf(D, p.y, -qb), p.y, qa);
    cc[n] = (v2f){c1, c0};
  }
  __syncthreads();

  const int w0 = seg * 256 + t;        // pixels: w0, w0+64, w0+128, w0+192
  const v2f ya = {(float)w0 * scale, (float)(w0 + 64) * scale};
  const v2f yb = {(float)(w0 + 128) * scale, (float)(w0 + 192) * scale};

  v2f rg0 = {0.f, 0.f};   // (r,g) px0
  v2f rg1 = {0.f, 0.f};   // (r,g) px1
  v2f rg2 = {0.f, 0.f};   // (r,g) px2
  v2f rg3 = {0.f, 0.f};   // (r,g) px3
  v2f b01 = {0.f, 0.f};   // (b px0, b px1)
  v2f b23 = {0.f, 0.f};   // (b px2, b px3)

#pragma unroll 8
  for (int n = 0; n < N_GAUSS; ++n) {
    const v2f k = cc[n];               // broadcast ds_read_b64
    const float4 s = gpb[n];           // uniform -> s_load_dwordx4

    v2f qa = __builtin_elementwise_fma((v2f){s.x, s.x}, ya, (v2f){k.x, k.x});
    qa     = __builtin_elementwise_fma(qa, ya, (v2f){k.y, k.y});
    v2f qb = __builtin_elementwise_fma((v2f){s.x, s.x}, yb, (v2f){k.x, k.x});
    qb     = __builtin_elementwise_fma(qb, yb, (v2f){k.y, k.y});

    const float v0 = __builtin_amdgcn_exp2f(qa.x);
    const float v1 = __builtin_amdgcn_exp2f(qa.y);
    const float v2 = __builtin_amdgcn_exp2f(qb.x);
    const float v3 = __builtin_amdgcn_exp2f(qb.y);

    const v2f wrg = {s.y, s.z};
    const v2f wbb = {s.w, s.w};
    rg0 = __builtin_elementwise_fma((v2f){v0, v0}, wrg, rg0);
    rg1 = __builtin_elementwise_fma((v2f){v1, v1}, wrg, rg1);
    rg2 = __builtin_elementwise_fma((v2f){v2, v2}, wrg, rg2);
    rg3 = __builtin_elementwise_fma((v2f){v3, v3}, wrg, rg3);
    b01 = __builtin_elementwise_fma((v2f){v0, v1}, wbb, b01);
    b23 = __builtin_elementwise_fma((v2f){v2, v3}, wbb, b23);
  }

  float* o = out + ((size_t)h * W_DIM + w0) * 3;
  o[0] = rg0.x; o[1] = rg0.y; o[2] = b01.x;
  o = out + ((size_t)h * W_DIM + w0 + 64) * 3;
  o[0] = rg1.x; o[1] = rg1.y; o[2] = b01.y;
  o = out + ((size_t)h * W_DIM + w0 + 128) * 3;
  o[0] = rg2.x; o[1] = rg2.y; o[2] = b23.x;
  o = out + ((size_t)h * W_DIM + w0 + 192) * 3;
  o[0] = rg3.x; o[1] = rg3.y; o[2] = b23.y;
}

extern "C" void kernel_launch(void* const* d_in, const int* in_sizes, int n_in,
                              void* d_out, int out_size, void* d_ws, size_t ws_size,
                              hipStream_t stream) {
  const float* means  = (const float*)d_in[0];   // (N,2,1)
  const float* covs   = (const float*)d_in[1];   // (N,2,2)
  const float* colors = (const float*)d_in[2];   // (N,4)
  float4* gpa = (float4*)d_ws;                   // 16 KB
  float4* gpb = gpa + N_GAUSS;                   // 16 KB
  float* out = (float*)d_out;                    // (768,768,3) fp32

  prep_kernel<<<dim3(N_GAUSS / 256), dim3(256), 0, stream>>>(
      means, covs, colors, gpa, gpb);
  render_kernel<<<dim3((H_DIM * W_DIM) / (64 * 4)), dim3(64), 0, stream>>>(
      gpa, gpb, out);
}

// Round 5
// 174.823 us; speedup vs baseline: 1.0432x; 1.0432x over previous
//
#include <hip/hip_runtime.h>

#define N_GAUSS 1024
#define H_DIM 768
#define W_DIM 768

typedef float v2f __attribute__((ext_vector_type(2)));

// Single fused kernel. Each block = (row h, 256-px segment), 128 threads,
// 2 px/thread (w0, w0+128). Block-redundant prep: all 1024 gaussians' row
// coefficients computed per block into LDS (8 gaussians/thread, trivial).
//
// LDS layout is chosen so every hot-loop VOP3P operand is natively aligned:
//   cc4[n] = {D, c1, c0, wb}  -> ds_read_b128, aligned VGPR quad; all
//                                broadcasts are op_sel on aligned pairs
//   wrg[n] = {wr, wg}         -> ds_read_b64, aligned pair, direct src
// Hot loop per gaussian (2 px): 2 pk_fma (q) + 2 v_exp + 3 pk_fma (acc).
// q(y) = D*y^2 + c1*y + c0, with -0.5*log2(e) folded into D,c1,c0 so the
// exponential is a raw v_exp_f32 (exp2).
__global__ __launch_bounds__(128) void render_kernel(
    const float2* __restrict__ means2,   // (N,2,1) -> {mx,my} per n
    const float4* __restrict__ covs4,    // (N,2,2) -> {a,b,c,d} per n
    const float4* __restrict__ colors4,  // (N,4)   -> {cr,cg,cb,alpha}
    float* __restrict__ out) {
  __shared__ float4 cc4[N_GAUSS];  // {D, c1, c0, wb}
  __shared__ v2f    wrg[N_GAUSS];  // {wr, wg}

  const int h   = blockIdx.x / 3;
  const int seg = blockIdx.x % 3;
  const int t   = threadIdx.x;  // 0..127
  const float scale = 1.0f / 767.0f;
  const float x = (float)h * scale;
  const float L = -0.72134752044448170368f;  // -0.5 * log2(e)

  // Per-block prep: 8 gaussians per thread.
#pragma unroll
  for (int i = 0; i < N_GAUSS / 128; ++i) {
    const int n = i * 128 + t;
    const float2 m  = means2[n];
    const float4 cv = covs4[n];   // a,b,c,d
    const float4 co = colors4[n]; // cr,cg,cb,alpha
    const float inv = 1.0f / (cv.x * cv.w - cv.y * cv.z);
    const float A  = L * cv.w * inv;
    const float Bc = -L * (cv.y + cv.z) * inv;
    const float D  = L * cv.x * inv;
    const float dx = x - m.x;
    const float qa = A * dx * dx;
    const float qb = Bc * dx;
    const float c1 = fmaf(-2.0f * D, m.y, qb);
    const float c0 = fmaf(fmaf(D, m.y, -qb), m.y, qa);
    const float al = co.w;
    const float wr = al / (1.0f + expf(-co.x));
    const float wg = al / (1.0f + expf(-co.y));
    const float wb = al / (1.0f + expf(-co.z));
    cc4[n] = make_float4(D, c1, c0, wb);
    wrg[n] = (v2f){wr, wg};
  }
  __syncthreads();

  const int w0 = seg * 256 + t;
  const int w1 = w0 + 128;
  const v2f y  = {(float)w0 * scale, (float)w1 * scale};
  const v2f y2 = y * y;

  v2f rg0 = {0.f, 0.f};   // (r,g) px0
  v2f rg1 = {0.f, 0.f};   // (r,g) px1
  v2f b01 = {0.f, 0.f};   // (b px0, b px1)

#pragma unroll 8
  for (int n = 0; n < N_GAUSS; ++n) {
    const float4 P = cc4[n];   // ds_read_b128 broadcast (conflict-free)
    const v2f    w = wrg[n];   // ds_read_b64 broadcast

    // q = D*y^2 + c1*y + c0   (all broadcasts are op_sel on aligned pairs)
    v2f q = __builtin_elementwise_fma((v2f){P.y, P.y}, y, (v2f){P.z, P.z});
    q     = __builtin_elementwise_fma((v2f){P.x, P.x}, y2, q);

    const float v0 = __builtin_amdgcn_exp2f(q.x);
    const float v1 = __builtin_amdgcn_exp2f(q.y);

    rg0 = __builtin_elementwise_fma((v2f){v0, v0}, w, rg0);
    rg1 = __builtin_elementwise_fma((v2f){v1, v1}, w, rg1);
    b01 = __builtin_elementwise_fma((v2f){v0, v1}, (v2f){P.w, P.w}, b01);
  }

  float* o0 = out + ((size_t)h * W_DIM + w0) * 3;
  o0[0] = rg0.x; o0[1] = rg0.y; o0[2] = b01.x;
  float* o1 = out + ((size_t)h * W_DIM + w1) * 3;
  o1[0] = rg1.x; o1[1] = rg1.y; o1[2] = b01.y;
}

extern "C" void kernel_launch(void* const* d_in, const int* in_sizes, int n_in,
                              void* d_out, int out_size, void* d_ws, size_t ws_size,
                              hipStream_t stream) {
  const float2* means2  = (const float2*)d_in[0];   // (N,2,1)
  const float4* covs4   = (const float4*)d_in[1];   // (N,2,2)
  const float4* colors4 = (const float4*)d_in[2];   // (N,4)
  float* out = (float*)d_out;                       // (768,768,3) fp32

  render_kernel<<<dim3((H_DIM * W_DIM) / (128 * 2)), dim3(128), 0, stream>>>(
      means2, covs4, colors4, out);
}

// Round 8
// 144.003 us; speedup vs baseline: 1.2664x; 1.2140x over previous
//
#include <hip/hip_runtime.h>
#include <stdint.h>

#define N_GAUSS 1024
#define H_DIM 768
#define W_DIM 768
#define WL_STRIDE 1040  // fp16 row stride: bank offset 8/row -> 2-way (free)

typedef _Float16 half8  __attribute__((ext_vector_type(8)));
typedef __fp16   fp16x2 __attribute__((ext_vector_type(2)));
typedef float    f32x4  __attribute__((ext_vector_type(4)));
typedef uint32_t u32x4  __attribute__((ext_vector_type(4)));

// image[px][ch] = sum_g vals[px][g] * W[g][ch]  -> MFMA 16x16x32 f16.
// Wave = 64 px of one row (4 m-tiles of 16). K-loop: 32 tiles of 32 gaussians.
//   A[m = lane&15][k = quad*8 + j]            (m120-verified)
//   B[n = lane&15][k = quad*8 + j]            (same k indexing as A)
//   C/D: col = lane&15 (ch), row = quad*4+reg (px)   (m89-verified)
// q(y) = D*y^2 + c1*y + c0 per (row, gaussian); -0.5*log2(e) folded in so
// vals = v_exp_f32(q); fp16 via v_cvt_pkrtz.
//
// LDS coeffs: packed-6 layout. Per (kt, quad): 6 float4s = 24 floats holding
// {D,c1,c0} x 8 gaussians tightly (bijective; no swizzle collisions).
// Float index: kt*96 + quad*24 + j*3 + c.  Quad stride 96 B -> bank starts
// {0,24,16,8}: conflict-free b128 reads. W: wl[n][k], n in {r,g,b,zero},
// row stride 1040 fp16 -> exactly 2-way bank aliasing (free).
__global__ __launch_bounds__(256) void render_kernel(
    const float2* __restrict__ means2,   // (N,2,1) -> {mx,my}
    const float4* __restrict__ covs4,    // (N,2,2) -> {a,b,c,d}
    const float4* __restrict__ colors4,  // (N,4)   -> {cr,cg,cb,alpha}
    float* __restrict__ out) {
  __shared__ __align__(16) float ccf[32 * 96];             // 12 KB
  __shared__ __align__(16) _Float16 wl[4 * WL_STRIDE];     // 8320 B

  const int t   = threadIdx.x;          // 0..255
  const int h   = blockIdx.x / 3;       // row
  const int seg = blockIdx.x % 3;       // 256-px segment
  const float scale = 1.0f / 767.0f;
  const float x = (float)h * scale;
  const float L = -0.72134752044448170368f;  // -0.5 * log2(e)

  // ---- Block prep: 4 gaussians per thread ----
#pragma unroll
  for (int i = 0; i < 4; ++i) {
    const int g = i * 256 + t;
    const float2 mn = means2[g];
    const float4 cv = covs4[g];    // a,b,c,d
    const float4 co = colors4[g];  // cr,cg,cb,alpha
    const float inv = 1.0f / (cv.x * cv.w - cv.y * cv.z);
    const float A  = L * cv.w * inv;
    const float Bc = -L * (cv.y + cv.z) * inv;
    const float D  = L * cv.x * inv;
    const float dx = x - mn.x;
    const float qa = A * dx * dx;
    const float qb = Bc * dx;
    const float c1 = fmaf(-2.0f * D, mn.y, qb);
    const float c0 = fmaf(fmaf(D, mn.y, -qb), mn.y, qa);
    const float al = co.w;
    const float wr = al / (1.0f + expf(-co.x));
    const float wg = al / (1.0f + expf(-co.y));
    const float wb = al / (1.0f + expf(-co.z));
    const int kt_g = g >> 5, q_g = (g >> 3) & 3, j_g = g & 7;
    float* dst = &ccf[kt_g * 96 + q_g * 24 + j_g * 3];
    dst[0] = D; dst[1] = c1; dst[2] = c0;
    wl[0 * WL_STRIDE + g] = (_Float16)wr;
    wl[1 * WL_STRIDE + g] = (_Float16)wg;
    wl[2 * WL_STRIDE + g] = (_Float16)wb;
    wl[3 * WL_STRIDE + g] = (_Float16)0.0f;
  }
  __syncthreads();

  // ---- Per-wave setup ----
  const int lane   = t & 63;
  const int waveid = t >> 6;
  const int m    = lane & 15;
  const int quad = lane >> 4;
  const int px_base = seg * 256 + waveid * 64;   // 4 m-tiles: +0,16,32,48
  float y[4];
#pragma unroll
  for (int r = 0; r < 4; ++r) y[r] = (float)(px_base + 16 * r + m) * scale;
  const int n4 = (m < 3) ? m : 3;

  const float4* cbase = (const float4*)ccf + quad * 6;     // + kt*24
  const _Float16* wbase = &wl[n4 * WL_STRIDE + quad * 8];  // + kt*32

  f32x4 acc[4] = {{0.f,0.f,0.f,0.f},{0.f,0.f,0.f,0.f},
                  {0.f,0.f,0.f,0.f},{0.f,0.f,0.f,0.f}};

  for (int kt = 0; kt < 32; ++kt) {
    const float4* cp = cbase + kt * 24;
    float cf[24];
#pragma unroll
    for (int i = 0; i < 6; ++i) *(float4*)&cf[4 * i] = cp[i];  // 6x b128

    const half8 b = *(const half8*)(wbase + kt * 32);

    u32x4 pa[4];
#pragma unroll
    for (int r = 0; r < 4; ++r) {
      const float yr = y[r];
      float e[8];
#pragma unroll
      for (int j = 0; j < 8; ++j) {
        const float q = fmaf(fmaf(cf[3 * j], yr, cf[3 * j + 1]), yr,
                             cf[3 * j + 2]);
        e[j] = __builtin_amdgcn_exp2f(q);
      }
#pragma unroll
      for (int jj = 0; jj < 4; ++jj) {
        const fp16x2 hp = __builtin_amdgcn_cvt_pkrtz(e[2 * jj], e[2 * jj + 1]);
        pa[r][jj] = __builtin_bit_cast(uint32_t, hp);
      }
    }
#pragma unroll
    for (int r = 0; r < 4; ++r) {
      acc[r] = __builtin_amdgcn_mfma_f32_16x16x32_f16(
          __builtin_bit_cast(half8, pa[r]), b, acc[r], 0, 0, 0);
    }
  }

  // ---- Epilogue: lanes with channel m<3 write 4 px per m-tile ----
  if (m < 3) {
#pragma unroll
    for (int r = 0; r < 4; ++r) {
#pragma unroll
      for (int reg = 0; reg < 4; ++reg) {
        const int px = px_base + 16 * r + quad * 4 + reg;
        out[((size_t)h * W_DIM + px) * 3 + m] = acc[r][reg];
      }
    }
  }
}

extern "C" void kernel_launch(void* const* d_in, const int* in_sizes, int n_in,
                              void* d_out, int out_size, void* d_ws, size_t ws_size,
                              hipStream_t stream) {
  const float2* means2  = (const float2*)d_in[0];   // (N,2,1)
  const float4* covs4   = (const float4*)d_in[1];   // (N,2,2)
  const float4* colors4 = (const float4*)d_in[2];   // (N,4)
  float* out = (float*)d_out;                       // (768,768,3) fp32

  // 2304 blocks = 768 rows x 3 segments; 256 thr = 4 waves x 64 px.
  render_kernel<<<dim3(H_DIM * 3), dim3(256), 0, stream>>>(
      means2, covs4, colors4, out);
}

// Round 10
// 124.690 us; speedup vs baseline: 1.4626x; 1.1549x over previous
//
#include <hip/hip_runtime.h>
#include <stdint.h>

#define N_GAUSS 1024
#define H_DIM 768
#define W_DIM 768
#define WL_STRIDE 1040  // fp16 W row stride: row bank offset 8 -> 2-way (free)

typedef _Float16 half8  __attribute__((ext_vector_type(8)));
typedef __fp16   fp16x2 __attribute__((ext_vector_type(2)));
typedef float    f32x4  __attribute__((ext_vector_type(4)));
typedef float    v2f    __attribute__((ext_vector_type(2)));
typedef uint32_t u32x4  __attribute__((ext_vector_type(4)));

// v(y) = exp2(q(y)), q = D*y^2 + c1*y + c0 (-0.5*log2e folded in; q <= 0).
// Along a row with step Delta (16 px), v follows an exact 2nd-order
// multiplicative recurrence:
//   v_{r+1}   = v_r * rho_r,   rho_{r+1} = rho_r * sigma
//   rho_0 = exp2(q(y0+Delta)-q(y0)) = exp2(Delta*(D*(2y0+Delta)+c1))
//   sigma = exp2(2*D*Delta^2)            (row-independent, stored in LDS)
// -> 2 exps per (gaussian,lane) cover 8 m-tiles (128 px). All chain values
// bounded (v in [0,1], rho ~ 2^±3.3, sigma ~ 1): fp32-safe, fp16 only at
// the final cvt_pkrtz (same numerics as the R7 direct version).
//
// MFMA 16x16x32 f16: A[m=lane&15][k=quad*8+j]; C/D col=lane&15 (ch),
// row=quad*4+reg (px). Coeff LDS: float4 {D,c1,c0,sigma} per gaussian,
// [kt][quad][slot0..8] with 9-slot pad -> quad bank starts {0,4,8,12}:
// conflict-free b128. W rows {r,g,b,0} stride 1040 fp16 (2-way = free).
__global__ __launch_bounds__(128) void render_kernel(
    const float2* __restrict__ means2,   // (N,2,1) -> {mx,my}
    const float4* __restrict__ covs4,    // (N,2,2) -> {a,b,c,d}
    const float4* __restrict__ colors4,  // (N,4)   -> {cr,cg,cb,alpha}
    float* __restrict__ out) {
  __shared__ __align__(16) float4 ccf4[32 * 4 * 9];     // 18,432 B
  __shared__ __align__(16) _Float16 wl[4 * WL_STRIDE];  // 8,320 B

  const int t   = threadIdx.x;          // 0..127
  const int h   = blockIdx.x / 3;       // image row
  const int seg = blockIdx.x % 3;       // 256-px segment
  const float scale = 1.0f / 767.0f;
  const float x = (float)h * scale;
  const float L = -0.72134752044448170368f;  // -0.5 * log2(e)
  const float Delta = 16.0f * scale;

  // ---- Block prep: 8 gaussians per thread ----
#pragma unroll
  for (int i = 0; i < 8; ++i) {
    const int g = i * 128 + t;
    const float2 mn = means2[g];
    const float4 cv = covs4[g];    // a,b,c,d
    const float4 co = colors4[g];  // cr,cg,cb,alpha
    const float inv = 1.0f / (cv.x * cv.w - cv.y * cv.z);
    const float A  = L * cv.w * inv;
    const float Bc = -L * (cv.y + cv.z) * inv;
    const float D  = L * cv.x * inv;
    const float dx = x - mn.x;
    const float qa = A * dx * dx;
    const float qb = Bc * dx;
    const float c1 = fmaf(-2.0f * D, mn.y, qb);
    const float c0 = fmaf(fmaf(D, mn.y, -qb), mn.y, qa);
    const float sg = __builtin_amdgcn_exp2f(2.0f * D * Delta * Delta);
    ccf4[(g >> 5) * 36 + ((g >> 3) & 3) * 9 + (g & 7)] =
        make_float4(D, c1, c0, sg);
    const float al = co.w;
    wl[0 * WL_STRIDE + g] = (_Float16)(al / (1.0f + expf(-co.x)));
    wl[1 * WL_STRIDE + g] = (_Float16)(al / (1.0f + expf(-co.y)));
    wl[2 * WL_STRIDE + g] = (_Float16)(al / (1.0f + expf(-co.z)));
    wl[3 * WL_STRIDE + g] = (_Float16)0.0f;
  }
  __syncthreads();

  // ---- Per-wave setup: wave = 128 px (8 m-tiles of 16) ----
  const int lane   = t & 63;
  const int waveid = t >> 6;            // 0..1
  const int m    = lane & 15;
  const int quad = lane >> 4;
  const int px0  = seg * 256 + waveid * 128;
  const float y0 = (float)(px0 + m) * scale;
  const float u  = fmaf(2.0f, y0, Delta);   // for rho_0 exponent
  const int n4 = (m < 3) ? m : 3;

  const float4* cbase = ccf4 + quad * 9;                   // + kt*36
  const _Float16* wbase = &wl[n4 * WL_STRIDE + quad * 8];  // + kt*32

  f32x4 acc[8];
#pragma unroll
  for (int r = 0; r < 8; ++r) acc[r] = (f32x4){0.f, 0.f, 0.f, 0.f};

  for (int kt = 0; kt < 32; ++kt) {
    const float4* cp = cbase + kt * 36;
    float4 c[8];
#pragma unroll
    for (int j = 0; j < 8; ++j) c[j] = cp[j];   // 8x ds_read_b128, bank-clean

    const half8 b = *(const half8*)(wbase + kt * 32);

    // anchors + ratios (2 exps per gaussian, bounded fp32)
    v2f vv[4], rr[4], ss[4];
#pragma unroll
    for (int j = 0; j < 8; ++j) {
      const float q0  = fmaf(fmaf(c[j].x, y0, c[j].y), y0, c[j].z);
      const float rex = Delta * fmaf(c[j].x, u, c[j].y);
      vv[j >> 1][j & 1] = __builtin_amdgcn_exp2f(q0);
      rr[j >> 1][j & 1] = __builtin_amdgcn_exp2f(rex);
      ss[j >> 1][j & 1] = c[j].w;
    }

#pragma unroll
    for (int r = 0; r < 8; ++r) {
      u32x4 pa;
#pragma unroll
      for (int p = 0; p < 4; ++p) {
        const fp16x2 hp = __builtin_amdgcn_cvt_pkrtz(vv[p].x, vv[p].y);
        pa[p] = __builtin_bit_cast(uint32_t, hp);
      }
      acc[r] = __builtin_amdgcn_mfma_f32_16x16x32_f16(
          __builtin_bit_cast(half8, pa), b, acc[r], 0, 0, 0);
      if (r < 7) {
#pragma unroll
        for (int p = 0; p < 4; ++p) {   // v_pk_mul_f32 chains
          vv[p] *= rr[p];
          rr[p] *= ss[p];
        }
      }
    }
  }

  // ---- Epilogue: lanes with channel m<3 write 4 px per m-tile ----
  if (m < 3) {
#pragma unroll
    for (int r = 0; r < 8; ++r) {
#pragma unroll
      for (int reg = 0; reg < 4; ++reg) {
        const int px = px0 + 16 * r + quad * 4 + reg;
        out[((size_t)h * W_DIM + px) * 3 + m] = acc[r][reg];
      }
    }
  }
}

extern "C" void kernel_launch(void* const* d_in, const int* in_sizes, int n_in,
                              void* d_out, int out_size, void* d_ws, size_t ws_size,
                              hipStream_t stream) {
  const float2* means2  = (const float2*)d_in[0];   // (N,2,1)
  const float4* covs4   = (const float4*)d_in[1];   // (N,2,2)
  const float4* colors4 = (const float4*)d_in[2];   // (N,4)
  float* out = (float*)d_out;                       // (768,768,3) fp32

  // 2304 blocks = 768 rows x 3 segs; 128 thr = 2 waves x 128 px.
  render_kernel<<<dim3(H_DIM * 3), dim3(128), 0, stream>>>(
      means2, covs4, colors4, out);
}

// Round 11
// 116.852 us; speedup vs baseline: 1.5607x; 1.0671x over previous
//
#include <hip/hip_runtime.h>
#include <stdint.h>

#define N_GAUSS 1024
#define H_DIM 768
#define W_DIM 768
#define WL_STRIDE 1040  // fp16 W row stride: row bank offset 8 -> 2-way (free)

typedef _Float16 half8  __attribute__((ext_vector_type(8)));
typedef __fp16   fp16x2 __attribute__((ext_vector_type(2)));
typedef float    f32x4  __attribute__((ext_vector_type(4)));
typedef float    v2f    __attribute__((ext_vector_type(2)));
typedef uint32_t u32x4  __attribute__((ext_vector_type(4)));

// v(y) = exp2(q(y)), q = D*y^2 + c1*y + c0 (-0.5*log2e folded in; q <= 0).
// Along a row with step Delta (16 px), v follows an exact 2nd-order
// multiplicative recurrence:
//   v_{r+1}   = v_r * rho_r,   rho_{r+1} = rho_r * sigma
//   rho_0 = exp2(q(y0+Delta)-q(y0)) = exp2(Delta*(D*(2y0+Delta)+c1))
//   sigma = exp2(2*D*Delta^2)            (row-independent, stored in LDS)
// -> 2 exps per (gaussian,lane) cover 8 m-tiles (128 px). All chain values
// bounded (v in [0,1], rho ~ 2^±3.3, sigma ~ 1): fp32-safe, fp16 only at
// the final cvt_pkrtz.
//
// R10 geometry: one block per image row: 384 thr = 6 waves x 128 px,
// 768 blocks = exactly 3 blocks/CU (LDS 27 KB x 3 = 81 KB), 18 waves/CU,
// no dispatch tail. Hot loop identical to R9 (which passed, absmax 0.5).
//
// MFMA 16x16x32 f16: A[m=lane&15][k=quad*8+j]; C/D col=lane&15 (ch),
// row=quad*4+reg (px). Coeff LDS: float4 {D,c1,c0,sigma} per gaussian,
// [kt][quad][slot0..8] with 9-slot pad -> quad bank starts {0,4,8,12}:
// conflict-free b128. W rows {r,g,b,0} stride 1040 fp16 (2-way = free).
__global__ __launch_bounds__(384) void render_kernel(
    const float2* __restrict__ means2,   // (N,2,1) -> {mx,my}
    const float4* __restrict__ covs4,    // (N,2,2) -> {a,b,c,d}
    const float4* __restrict__ colors4,  // (N,4)   -> {cr,cg,cb,alpha}
    float* __restrict__ out) {
  __shared__ __align__(16) float4 ccf4[32 * 4 * 9];     // 18,432 B
  __shared__ __align__(16) _Float16 wl[4 * WL_STRIDE];  // 8,320 B

  const int t = threadIdx.x;   // 0..383
  const int h = blockIdx.x;    // image row
  const float scale = 1.0f / 767.0f;
  const float x = (float)h * scale;
  const float L = -0.72134752044448170368f;  // -0.5 * log2(e)
  const float Delta = 16.0f * scale;

  // ---- Block prep ----
  for (int g = t; g < N_GAUSS; g += 384) {
    const float2 mn = means2[g];
    const float4 cv = covs4[g];    // a,b,c,d
    const float4 co = colors4[g];  // cr,cg,cb,alpha
    const float inv = 1.0f / (cv.x * cv.w - cv.y * cv.z);
    const float A  = L * cv.w * inv;
    const float Bc = -L * (cv.y + cv.z) * inv;
    const float D  = L * cv.x * inv;
    const float dx = x - mn.x;
    const float qa = A * dx * dx;
    const float qb = Bc * dx;
    const float c1 = fmaf(-2.0f * D, mn.y, qb);
    const float c0 = fmaf(fmaf(D, mn.y, -qb), mn.y, qa);
    const float sg = __builtin_amdgcn_exp2f(2.0f * D * Delta * Delta);
    ccf4[(g >> 5) * 36 + ((g >> 3) & 3) * 9 + (g & 7)] =
        make_float4(D, c1, c0, sg);
    const float al = co.w;
    wl[0 * WL_STRIDE + g] = (_Float16)(al / (1.0f + expf(-co.x)));
    wl[1 * WL_STRIDE + g] = (_Float16)(al / (1.0f + expf(-co.y)));
    wl[2 * WL_STRIDE + g] = (_Float16)(al / (1.0f + expf(-co.z)));
    wl[3 * WL_STRIDE + g] = (_Float16)0.0f;
  }
  __syncthreads();

  // ---- Per-wave setup: wave = 128 px (8 m-tiles of 16) ----
  const int lane = t & 63;
  const int widx = t >> 6;              // 0..5
  const int m    = lane & 15;
  const int quad = lane >> 4;
  const int px0  = widx * 128;
  const float y0 = (float)(px0 + m) * scale;
  const float u  = fmaf(2.0f, y0, Delta);   // for rho_0 exponent
  const int n4 = (m < 3) ? m : 3;

  const float4* cbase = ccf4 + quad * 9;                   // + kt*36
  const _Float16* wbase = &wl[n4 * WL_STRIDE + quad * 8];  // + kt*32

  f32x4 acc[8];
#pragma unroll
  for (int r = 0; r < 8; ++r) acc[r] = (f32x4){0.f, 0.f, 0.f, 0.f};

  for (int kt = 0; kt < 32; ++kt) {
    const float4* cp = cbase + kt * 36;
    float4 c[8];
#pragma unroll
    for (int j = 0; j < 8; ++j) c[j] = cp[j];   // 8x ds_read_b128, bank-clean

    const half8 b = *(const half8*)(wbase + kt * 32);

    // anchors + ratios (2 exps per gaussian, bounded fp32)
    v2f vv[4], rr[4], ss[4];
#pragma unroll
    for (int j = 0; j < 8; ++j) {
      const float q0  = fmaf(fmaf(c[j].x, y0, c[j].y), y0, c[j].z);
      const float rex = Delta * fmaf(c[j].x, u, c[j].y);
      vv[j >> 1][j & 1] = __builtin_amdgcn_exp2f(q0);
      rr[j >> 1][j & 1] = __builtin_amdgcn_exp2f(rex);
      ss[j >> 1][j & 1] = c[j].w;
    }

#pragma unroll
    for (int r = 0; r < 8; ++r) {
      u32x4 pa;
#pragma unroll
      for (int p = 0; p < 4; ++p) {
        const fp16x2 hp = __builtin_amdgcn_cvt_pkrtz(vv[p].x, vv[p].y);
        pa[p] = __builtin_bit_cast(uint32_t, hp);
      }
      acc[r] = __builtin_amdgcn_mfma_f32_16x16x32_f16(
          __builtin_bit_cast(half8, pa), b, acc[r], 0, 0, 0);
      if (r < 7) {
#pragma unroll
        for (int p = 0; p < 4; ++p) {   // v_pk_mul_f32 chains
          vv[p] *= rr[p];
          rr[p] *= ss[p];
        }
      }
    }
  }

  // ---- Epilogue: lanes with channel m<3 write 4 px per m-tile ----
  if (m < 3) {
#pragma unroll
    for (int r = 0; r < 8; ++r) {
#pragma unroll
      for (int reg = 0; reg < 4; ++reg) {
        const int px = px0 + 16 * r + quad * 4 + reg;
        out[((size_t)h * W_DIM + px) * 3 + m] = acc[r][reg];
      }
    }
  }
}

extern "C" void kernel_launch(void* const* d_in, const int* in_sizes, int n_in,
                              void* d_out, int out_size, void* d_ws, size_t ws_size,
                              hipStream_t stream) {
  const float2* means2  = (const float2*)d_in[0];   // (N,2,1)
  const float4* covs4   = (const float4*)d_in[1];   // (N,2,2)
  const float4* colors4 = (const float4*)d_in[2];   // (N,4)
  float* out = (float*)d_out;                       // (768,768,3) fp32

  // 768 blocks = one per row; 384 thr = 6 waves x 128 px; 3 blocks/CU exact.
  render_kernel<<<dim3(H_DIM), dim3(384), 0, stream>>>(
      means2, covs4, colors4, out);
}